// Round 12
// baseline (422.848 us; speedup 1.0000x reference)
//
#include <hip/hip_runtime.h>
#include <math.h>

#define EPS 1e-9f

constexpr int B_ = 8, N_ = 2048, M_ = 2048;
constexpr int THREADS = 512;               // 8 waves/block
constexpr int WAVES = 8;
constexpr int RPW = 4;                     // rows per wave (wave-uniform rows!)
constexpr int RPB = WAVES * RPW;           // 32 rows per block
constexpr int BPB = N_ / RPB;              // 64 blocks per batch
constexpr int GRID = B_ * BPB;             // 512 blocks = 2/CU

__global__ __launch_bounds__(256) void init_kernel(float* rL, float* fb,
                                                   float* ss0, float* out) {
    int i = blockIdx.x * blockDim.x + threadIdx.x;
    if (i < B_ * N_) { rL[i] = 1.f; fb[i] = 0.f; ss0[i] = 0.f; }
    if (i < B_) out[i] = 0.f;
}

// Merged sort (round-8): key+index bitonic, wave-local phases barrier-free.
__global__ __launch_bounds__(1024) void sort_kernel(
        const float* __restrict__ xyz1, const float* __restrict__ xyz2,
        float4* __restrict__ out1, float4* __restrict__ out2,
        float2* __restrict__ bounds) {
    __shared__ float kx[2048];
    __shared__ int   ki[2048];
    const int bb = blockIdx.x;
    const bool isB = (bb >= B_);
    const int b = isB ? bb - B_ : bb;
    const float* __restrict__ src = isB ? xyz2 : xyz1;
    float4* __restrict__ dst = isB ? out2 : out1;
    const int t = threadIdx.x;

    for (int i = t; i < 2048; i += 1024) {
        kx[i] = src[((size_t)b * 2048 + i) * 3];
        ki[i] = i;
    }
    __syncthreads();

    bool prev_cross = false;
    for (int ksz = 2; ksz <= 2048; ksz <<= 1) {
        for (int j = ksz >> 1; j >= 1; j >>= 1) {
            const bool cross = (j >= 128);
            if (cross || prev_cross) __syncthreads();
            else __builtin_amdgcn_wave_barrier();
            const int i  = t + (t & ~(j - 1));
            const int pr = i + j;
            const bool up = ((i & ksz) == 0);
            const float ax = kx[i], bx = kx[pr];
            if ((ax > bx) == up) {
                const int ai = ki[i], bi = ki[pr];
                kx[i] = bx; kx[pr] = ax;
                ki[i] = bi; ki[pr] = ai;
            }
            prev_cross = cross;
        }
    }
    __syncthreads();

    for (int i = t; i < 2048; i += 1024) {
        const float* q = src + ((size_t)b * 2048 + ki[i]) * 3;
        dst[(size_t)b * 2048 + i] = make_float4(q[0], q[1], q[2], 0.f);
    }
    if (isB && t < 32)
        bounds[b * 32 + t] = make_float2(kx[t * 64], kx[t * 64 + 63]);
}

// Round-11 + round-12 change: EC-CACHE VIA HALF-PASSES on dense waves.
// The colsum sweep recomputed exp2(-s2) (+~8 VALU/pair) already produced by
// sweep1. Cache ecw = ec*rn in registers: ecw[32][2] = 64 VGPR fits the
// 128-reg cap if rows are processed in TWO half-passes of 2 (round-10's
// [32][4]=128 forced silent rematerialization). Dense colsum collapses to
// 1 fma/pair: -30% total issue. Per-row k-order unchanged; only colsum
// grouping/rounding changes (tolerance absorbs ulp-level, proven by rounds
// 2..11 reorderings). Masked / s0 / s9 / s10 paths byte-identical.
#define HALF_PASS(R0, R1, FIRST)                                              \
  {                                                                           \
    float ad0 = 0.f, ad1 = 0.f, ac0 = 0.f, ac1 = 0.f, pp0 = 0.f, pp1 = 0.f;   \
    _Pragma("unroll")                                                         \
    for (int k = 0; k < 32; ++k) {                                            \
      const int kk = (k << 6) + lane;                                         \
      const float4 c = sp[kk];                                                \
      const float  g = sg[kk];                                                \
      {                                                                       \
        const float dx = xv[R0]-c.x, dy = yv[R0]-c.y, dz = zv[R0]-c.z;        \
        const float s2 = dx*dx + dy*dy + dz*dz;                               \
        const float ec = __builtin_amdgcn_exp2f(-s2);                         \
        const float ew = ec * c.w;                                            \
        ecw[k][0] = ew;                                                       \
        const float e  = __builtin_amdgcn_exp2f(-4.f * s2) * g;               \
        ad0 += e;                                                             \
        ac0 += e * __builtin_amdgcn_sqrtf(s2);                                \
        pp0 += ew;                                                            \
      }                                                                       \
      {                                                                       \
        const float dx = xv[R1]-c.x, dy = yv[R1]-c.y, dz = zv[R1]-c.z;        \
        const float s2 = dx*dx + dy*dy + dz*dz;                               \
        const float ec = __builtin_amdgcn_exp2f(-s2);                         \
        const float ew = ec * c.w;                                            \
        ecw[k][1] = ew;                                                       \
        const float e  = __builtin_amdgcn_exp2f(-4.f * s2) * g;               \
        ad1 += e;                                                             \
        ac1 += e * __builtin_amdgcn_sqrtf(s2);                                \
        pp1 += ew;                                                            \
      }                                                                       \
    }                                                                         \
    _Pragma("unroll")                                                         \
    for (int off = 32; off >= 1; off >>= 1) {                                 \
      ad0 += __shfl_xor(ad0, off, 64); ac0 += __shfl_xor(ac0, off, 64);       \
      ad1 += __shfl_xor(ad1, off, 64); ac1 += __shfl_xor(ac1, off, 64);       \
      pp0 += __shfl_xor(pp0, off, 64); pp1 += __shfl_xor(pp1, off, 64);       \
    }                                                                         \
    const int i0 = b * N_ + nw + R0, i1 = b * N_ + nw + R1;                   \
    const float fo0 = fb[i0], fo1 = fb[i1];                                   \
    const float rl0 = rLb[i0], rl1 = rLb[i1];                                 \
    const float rn0 = fmaxf(rl0 - fo0 * ad0, 0.f);                            \
    const float rn1 = fmaxf(rl1 - fo1 * ad1, 0.f);                            \
    cw += fo0 * ac0; cw += fo1 * ac1;                                         \
    const float f0 = rn0 / (pp0 + EPS), f1 = rn1 / (pp1 + EPS);               \
    if (lane == 0) {                                                          \
      fb[i0] = f0; fb[i1] = f1; rLb[i0] = rn0; rLb[i1] = rn1;                 \
    }                                                                         \
    _Pragma("unroll")                                                         \
    for (int k = 0; k < 32; ++k) {                                            \
      const float v = ecw[k][0] * f0 + ecw[k][1] * f1;                        \
      if (FIRST) ssp[k] = v; else ssp[k] += v;                                \
    }                                                                         \
  }

__global__ __launch_bounds__(THREADS, 2) void fused_step(
        const float4* __restrict__ xyz1s, const float4* __restrict__ xyz2s,
        const float2* __restrict__ bounds2,
        float* __restrict__ rLb, float* __restrict__ fb,
        const float* __restrict__ rRp,   // rR(s-1) in   (unused if !has_p2)
        float* __restrict__ rRn_g,       // rR(s)  out   (designated block)
        const float* __restrict__ ssp_g, // ss(s-1) in   (unused if !has_p2)
        float* __restrict__ ssc_g,       // ss(s) atomic accumulate (pre-zeroed)
        float* __restrict__ ssz_g,       // ss(s+1) zeroed here for next kernel
        float* __restrict__ out,
        float ascale, float inva, int has_p2, int has_p1, int domask, int lcz)
{
    __shared__ __align__(16) float raw[8 * M_ + 2 * WAVES + 64];
    float4* sp    = (float4*)raw;
    float*  sg    = raw + 4 * M_;
    float*  ssl   = raw;
    float*  wcost = raw + 8 * M_;
    float*  sfn_l = raw + 8 * M_ + WAVES;
    float2* bnds  = (float2*)(raw + 8 * M_ + 2 * WAVES);

    const int b   = blockIdx.x / BPB;
    const int blk = blockIdx.x % BPB;
    const int n0  = blk * RPB;
    const int tid = threadIdx.x;
    const bool designated = (blk == 0);

    for (int m = tid; m < M_; m += THREADS) {
        const float4 q = xyz2s[b * M_ + m];
        float g = 0.f, rn = 1.f;
        if (has_p2) {
            const float rr = rRp[b * M_ + m];
            const float sv = ssp_g[b * M_ + m];
            const float ratio = fminf(rr / (sv + EPS), 1.f);
            g  = rr * ratio;
            rn = fmaxf(rr - sv * ratio, 0.f);
        }
        sp[m] = make_float4(q.x * ascale, q.y * ascale, q.z * ascale, rn);
        sg[m] = g;
        if (designated) {
            if (has_p1) rRn_g[b * M_ + m] = rn;
            ssz_g[b * M_ + m] = 0.f;
        }
    }
    if (tid < 32) {
        const float2 bb = bounds2[b * 32 + tid];
        bnds[tid] = make_float2(bb.x * ascale, bb.y * ascale);
    }
    __syncthreads();

    const int wave = tid >> 6, lane = tid & 63;
    const int nw = n0 + wave * RPW;

    float xv[RPW], yv[RPW], zv[RPW];
    #pragma unroll
    for (int r = 0; r < RPW; ++r) {
        const float4 q = xyz1s[b * N_ + nw + r];
        xv[r] = q.x * ascale; yv[r] = q.y * ascale; zv[r] = q.z * ascale;
    }

    unsigned mf = 0xffffffffu, mp = 0u;
    if (domask) {
        mf = 0u;
        for (int k = 0; k < 32; ++k) {
            const float2 bb = bnds[k];
            float t2 = 1e30f;
            #pragma unroll
            for (int r = 0; r < RPW; ++r) {
                const float t = fmaxf(fmaxf(bb.x - xv[r], xv[r] - bb.y), 0.f);
                t2 = fminf(t2, t * t);
            }
            if (t2 * 4.f <= 160.f)  mf |= (1u << k);
            else if (t2 <= 160.f)   mp |= (1u << k);
        }
    }
    const unsigned alive = mf | mp;
    const bool densew = has_p2 && has_p1 && domask && (mf == 0xffffffffu);

    float ssp[32];       // colsum partials (filled by cached OR recompute path)
    float cw = 0.f;

    if (densew) {
        // ---- cached dense path: two half-passes sharing ecw[32][2] ----
        float ecw[32][2];
        HALF_PASS(0, 1, true)
        HALF_PASS(2, 3, false)
        if (lane == 0) wcost[wave] = cw * inva;
    } else {
        float accd[RPW], accc[RPW], p[RPW];
        #pragma unroll
        for (int r = 0; r < RPW; ++r) { accd[r] = 0.f; accc[r] = 0.f; p[r] = 0.f; }

        if (has_p2 && has_p1 && domask) {
            // masked path (early steps; partially-dense waves)
            for (int k = 0; k < 32; ++k) {
                if (!((alive >> k) & 1u)) continue;
                const int kk = (k << 6) + lane;
                const float4 c = sp[kk];
                if ((mf >> k) & 1u) {
                    const float g = sg[kk];
                    #pragma unroll
                    for (int r = 0; r < RPW; ++r) {
                        const float dx = xv[r]-c.x, dy = yv[r]-c.y, dz = zv[r]-c.z;
                        const float s2 = dx*dx + dy*dy + dz*dz;
                        const float ec = __builtin_amdgcn_exp2f(-s2);
                        const float e  = __builtin_amdgcn_exp2f(-4.f * s2) * g;
                        accd[r] += e;
                        accc[r] += e * __builtin_amdgcn_sqrtf(s2);
                        p[r] += ec * c.w;
                    }
                } else {
                    #pragma unroll
                    for (int r = 0; r < RPW; ++r) {
                        const float dx = xv[r]-c.x, dy = yv[r]-c.y, dz = zv[r]-c.z;
                        const float s2 = dx*dx + dy*dy + dz*dz;
                        p[r] += __builtin_amdgcn_exp2f(-s2) * c.w;
                    }
                }
            }
        } else if (!has_p2) {
            for (int k = 0; k < 32; ++k) {
                if (!((alive >> k) & 1u)) continue;
                const int kk = (k << 6) + lane;
                const float4 c = sp[kk];
                #pragma unroll
                for (int r = 0; r < RPW; ++r) {
                    const float dx = xv[r]-c.x, dy = yv[r]-c.y, dz = zv[r]-c.z;
                    const float s2 = dx*dx + dy*dy + dz*dz;
                    p[r] += __builtin_amdgcn_exp2f(-s2) * c.w;
                }
            }
        } else if (has_p1) {
            // s=9: dense, branchless
            #pragma unroll 4
            for (int k = 0; k < 32; ++k) {
                const int kk = (k << 6) + lane;
                const float4 c = sp[kk];
                const float  g = sg[kk];
                #pragma unroll
                for (int r = 0; r < RPW; ++r) {
                    const float dx = xv[r]-c.x, dy = yv[r]-c.y, dz = zv[r]-c.z;
                    const float s2 = dx*dx + dy*dy + dz*dz;
                    const float e  = __builtin_amdgcn_exp2f(-s2) * g;
                    accd[r] += e;
                    accc[r] += e * __builtin_amdgcn_sqrtf(s2);
                    p[r] += c.w;
                }
            }
        } else {
            // s=10: dense, no exp
            #pragma unroll 4
            for (int k = 0; k < 32; ++k) {
                const int kk = (k << 6) + lane;
                const float4 c = sp[kk];
                const float  g = sg[kk];
                #pragma unroll
                for (int r = 0; r < RPW; ++r) {
                    const float dx = xv[r]-c.x, dy = yv[r]-c.y, dz = zv[r]-c.z;
                    const float s2 = dx*dx + dy*dy + dz*dz;
                    accd[r] += g;
                    accc[r] += g * __builtin_amdgcn_sqrtf(s2);
                }
            }
        }

        if (has_p2) {
            #pragma unroll
            for (int r = 0; r < RPW; ++r) {
                #pragma unroll
                for (int off = 32; off >= 1; off >>= 1) {
                    accd[r] += __shfl_xor(accd[r], off, 64);
                    accc[r] += __shfl_xor(accc[r], off, 64);
                }
            }
        }
        if (has_p1) {
            #pragma unroll
            for (int r = 0; r < RPW; ++r) {
                #pragma unroll
                for (int off = 32; off >= 1; off >>= 1)
                    p[r] += __shfl_xor(p[r], off, 64);
            }
        }

        float rl_new[RPW];
        if (has_p2) {
            #pragma unroll
            for (int r = 0; r < RPW; ++r) {
                const int idx = b * N_ + nw + r;
                const float fo = fb[idx];
                const float rl = rLb[idx];
                rl_new[r] = fmaxf(rl - fo * accd[r], 0.f);
                cw += fo * accc[r];
            }
        } else {
            #pragma unroll
            for (int r = 0; r < RPW; ++r) rl_new[r] = 1.f;
        }
        if (lane == 0) wcost[wave] = cw * inva;

        if (has_p1) {
            float fn[RPW];
            #pragma unroll
            for (int r = 0; r < RPW; ++r)
                fn[r] = rl_new[r] / (p[r] + EPS);
            if (lane == 0) {
                #pragma unroll
                for (int r = 0; r < RPW; ++r) {
                    const int idx = b * N_ + nw + r;
                    fb[idx]  = fn[r];
                    rLb[idx] = rl_new[r];
                }
            }
            if (!lcz) {
                if (alive == 0xffffffffu) {
                    // dense-alive recompute colsum (mp-mixed waves)
                    #pragma unroll 4
                    for (int k = 0; k < 32; ++k) {
                        const int kk = (k << 6) + lane;
                        const float4 c = sp[kk];
                        float acc = 0.f;
                        #pragma unroll
                        for (int r = 0; r < RPW; ++r) {
                            const float dx = xv[r]-c.x, dy = yv[r]-c.y, dz = zv[r]-c.z;
                            const float s2 = dx*dx + dy*dy + dz*dz;
                            acc += __builtin_amdgcn_exp2f(-s2) * fn[r];
                        }
                        ssp[k] = acc * c.w;
                    }
                } else {
                    for (int k = 0; k < 32; ++k) {
                        float sv = 0.f;
                        if ((alive >> k) & 1u) {
                            const int kk = (k << 6) + lane;
                            const float4 c = sp[kk];
                            float acc = 0.f;
                            #pragma unroll
                            for (int r = 0; r < RPW; ++r) {
                                const float dx = xv[r]-c.x, dy = yv[r]-c.y, dz = zv[r]-c.z;
                                const float s2 = dx*dx + dy*dy + dz*dz;
                                acc += __builtin_amdgcn_exp2f(-s2) * fn[r];
                            }
                            sv = acc * c.w;
                        }
                        ssp[k] = sv;
                    }
                }
            } else {
                // s=9: l2c == 0 -> ec == 1 -> ss(m) = rn(m) * sum_block(fn)
                if (lane == 0) sfn_l[wave] = fn[0] + fn[1] + fn[2] + fn[3];
            }
        }
    }

    // ---- common tail (barrier counts identical for all waves) ----
    if (has_p1) {
        if (!lcz) {
            __syncthreads();   // all sp/sg reads done -> ssl overlay safe
            #pragma unroll
            for (int k = 0; k < 32; ++k)
                ssl[wave * M_ + (k << 6) + lane] = ssp[k];
            __syncthreads();
            if (tid == 0 && has_p2) {
                float t = 0.f;
                #pragma unroll
                for (int w = 0; w < WAVES; ++w) t += wcost[w];
                atomicAdd(&out[b], t);
            }
            for (int m = tid; m < M_; m += THREADS) {
                const float sval = ssl[m]        + ssl[M_ + m]   + ssl[2*M_ + m]
                                 + ssl[3*M_ + m] + ssl[4*M_ + m] + ssl[5*M_ + m]
                                 + ssl[6*M_ + m] + ssl[7*M_ + m];
                if (sval != 0.f) atomicAdd(&ssc_g[b * M_ + m], sval);
            }
        } else {
            __syncthreads();
            if (tid == 0 && has_p2) {
                float t = 0.f;
                #pragma unroll
                for (int w = 0; w < WAVES; ++w) t += wcost[w];
                atomicAdd(&out[b], t);
            }
            float tot = 0.f;
            #pragma unroll
            for (int w = 0; w < WAVES; ++w) tot += sfn_l[w];
            for (int m = tid; m < M_; m += THREADS) {
                const float v = sp[m].w * tot;
                if (v != 0.f) atomicAdd(&ssc_g[b * M_ + m], v);
            }
        }
    } else {
        __syncthreads();
        if (tid == 0) {
            float t = 0.f;
            #pragma unroll
            for (int w = 0; w < WAVES; ++w) t += wcost[w];
            atomicAdd(&out[b], t);
        }
    }
}

extern "C" void kernel_launch(void* const* d_in, const int* in_sizes, int n_in,
                              void* d_out, int out_size, void* d_ws, size_t ws_size,
                              hipStream_t stream) {
    const float* xyz1 = (const float*)d_in[0];
    const float* xyz2 = (const float*)d_in[1];
    float* out = (float*)d_out;
    float* ws = (float*)d_ws;
    const int SZ = B_ * N_;          // == B_*M_ == 16384
    float* rL  = ws;
    float* fb  = ws + SZ;
    float* rRb[2] = { ws + 2*SZ, ws + 3*SZ };
    float* ssb[3] = { ws + 4*SZ, ws + 5*SZ, ws + 6*SZ };
    float2* bounds2 = (float2*)(ws + 7*SZ);
    float4* xyz1s   = (float4*)(ws + 7*SZ + 512);
    float4* xyz2s   = xyz1s + (size_t)B_ * N_;

    init_kernel<<<(SZ + 255) / 256, 256, 0, stream>>>(rL, fb, ssb[0], out);
    sort_kernel<<<2 * B_, 1024, 0, stream>>>(xyz1, xyz2, xyz1s, xyz2s, bounds2);

    constexpr float LOG2E = 1.4426950408889634f;
    static const float levels[10] = {
        -16384.f, -4096.f, -1024.f, -256.f, -64.f,
        -16.f, -4.f, -1.f, -0.25f, 0.f
    };
    for (int s = 0; s <= 10; ++s) {
        const int has_p2 = (s > 0);
        const int has_p1 = (s < 10);
        const int domask = (s <= 8);
        const int lcz    = (s == 9);
        const float lvl  = (s <= 8) ? levels[s] : levels[8];
        const float ascale = (s == 10) ? 1.f : sqrtf(-(lvl * LOG2E));
        const float inva   = 1.f / ascale;
        fused_step<<<GRID, THREADS, 0, stream>>>(
            xyz1s, xyz2s, bounds2, rL, fb,
            rRb[(s + 1) & 1], rRb[s & 1],
            ssb[(s + 2) % 3], ssb[s % 3], ssb[(s + 1) % 3],
            out, ascale, inva, has_p2, has_p1, domask, lcz);
    }
}

// Round 13
// 366.538 us; speedup vs baseline: 1.1536x; 1.1536x over previous
//
#include <hip/hip_runtime.h>
#include <math.h>

#define EPS 1e-9f

constexpr int B_ = 8, N_ = 2048, M_ = 2048;
constexpr int THREADS = 512;               // 8 waves/block
constexpr int WAVES = 8;
constexpr int RPW = 4;                     // rows per wave (wave-uniform rows!)
constexpr int RPB = WAVES * RPW;           // 32 rows per block
constexpr int BPB = N_ / RPB;              // 64 blocks per batch
constexpr int GRID = B_ * BPB;             // 512 blocks = 2/CU

__global__ __launch_bounds__(256) void init_kernel(float* rL, float* fb,
                                                   float* ss0, float* out) {
    int i = blockIdx.x * blockDim.x + threadIdx.x;
    if (i < B_ * N_) { rL[i] = 1.f; fb[i] = 0.f; ss0[i] = 0.f; }
    if (i < B_) out[i] = 0.f;
}

// Merged sort (round-8): key+index bitonic, wave-local phases barrier-free.
__global__ __launch_bounds__(1024) void sort_kernel(
        const float* __restrict__ xyz1, const float* __restrict__ xyz2,
        float4* __restrict__ out1, float4* __restrict__ out2,
        float2* __restrict__ bounds) {
    __shared__ float kx[2048];
    __shared__ int   ki[2048];
    const int bb = blockIdx.x;
    const bool isB = (bb >= B_);
    const int b = isB ? bb - B_ : bb;
    const float* __restrict__ src = isB ? xyz2 : xyz1;
    float4* __restrict__ dst = isB ? out2 : out1;
    const int t = threadIdx.x;

    for (int i = t; i < 2048; i += 1024) {
        kx[i] = src[((size_t)b * 2048 + i) * 3];
        ki[i] = i;
    }
    __syncthreads();

    bool prev_cross = false;
    for (int ksz = 2; ksz <= 2048; ksz <<= 1) {
        for (int j = ksz >> 1; j >= 1; j >>= 1) {
            const bool cross = (j >= 128);
            if (cross || prev_cross) __syncthreads();
            else __builtin_amdgcn_wave_barrier();
            const int i  = t + (t & ~(j - 1));
            const int pr = i + j;
            const bool up = ((i & ksz) == 0);
            const float ax = kx[i], bx = kx[pr];
            if ((ax > bx) == up) {
                const int ai = ki[i], bi = ki[pr];
                kx[i] = bx; kx[pr] = ax;
                ki[i] = bi; ki[pr] = ai;
            }
            prev_cross = cross;
        }
    }
    __syncthreads();

    for (int i = t; i < 2048; i += 1024) {
        const float* q = src + ((size_t)b * 2048 + ki[i]) * 3;
        dst[(size_t)b * 2048 + i] = make_float4(q[0], q[1], q[2], 0.f);
    }
    if (isB && t < 32)
        bounds[b * 32 + t] = make_float2(kx[t * 64], kx[t * 64 + 63]);
}

// Round-11 base + round-13 change: DOT-FORM DISTANCE on dense paths.
// t = (u.v - q2) - r2 = -s2 with u = 2*(a*x1) in regs, q2 = |a*x2|^2 packed
// into sg -> sgq = float2(g, -q2) (one ds_read_b64, no LDS growth, ssl
// overlay unchanged). ec = exp2(t) needs NO argument mul. Dense sweep
// 11 -> 10 VALU/pair; dense colsum 7 -> 5; total -17% with ZERO added live
// state (lesson of rounds 10/12: op cuts must not pin registers).
// sqrt gets fmaxf(-t,0) (dot-form cancellation guard, mirrors reference's
// max(d2,1e-20)). Masked paths (s<=4) and s=10 keep the exact
// squared-difference form.
__global__ __launch_bounds__(THREADS, 2) void fused_step(
        const float4* __restrict__ xyz1s, const float4* __restrict__ xyz2s,
        const float2* __restrict__ bounds2,
        float* __restrict__ rLb, float* __restrict__ fb,
        const float* __restrict__ rRp,   // rR(s-1) in   (unused if !has_p2)
        float* __restrict__ rRn_g,       // rR(s)  out   (designated block)
        const float* __restrict__ ssp_g, // ss(s-1) in   (unused if !has_p2)
        float* __restrict__ ssc_g,       // ss(s) atomic accumulate (pre-zeroed)
        float* __restrict__ ssz_g,       // ss(s+1) zeroed here for next kernel
        float* __restrict__ out,
        float ascale, float inva, int has_p2, int has_p1, int domask, int lcz)
{
    // raw[0:8192)      : sp  = float4 (a*x,a*y,a*z,rn)   32 KB
    // raw[8192:12288)  : sgq = float2 (g, -q2)           16 KB
    // raw[0:16384)     : ssl overlay (8 waves x 2048)    64 KB after barrier
    // raw[16384:..)    : wcost[8], sfn_l[8], bnds[32] (outside overlay)
    __shared__ __align__(16) float raw[8 * M_ + 2 * WAVES + 64];
    float4* sp    = (float4*)raw;
    float2* sgq   = (float2*)(raw + 4 * M_);
    float*  ssl   = raw;
    float*  wcost = raw + 8 * M_;
    float*  sfn_l = raw + 8 * M_ + WAVES;
    float2* bnds  = (float2*)(raw + 8 * M_ + 2 * WAVES);

    const int b   = blockIdx.x / BPB;
    const int blk = blockIdx.x % BPB;
    const int n0  = blk * RPB;
    const int tid = threadIdx.x;
    const bool designated = (blk == 0);

    for (int m = tid; m < M_; m += THREADS) {
        const float4 q = xyz2s[b * M_ + m];
        const float x = q.x * ascale, y = q.y * ascale, z = q.z * ascale;
        float g = 0.f, rn = 1.f;
        if (has_p2) {
            const float rr = rRp[b * M_ + m];
            const float sv = ssp_g[b * M_ + m];
            const float ratio = fminf(rr / (sv + EPS), 1.f);
            g  = rr * ratio;
            rn = fmaxf(rr - sv * ratio, 0.f);
        }
        sp[m]  = make_float4(x, y, z, rn);
        sgq[m] = make_float2(g, -(x * x + y * y + z * z));
        if (designated) {
            if (has_p1) rRn_g[b * M_ + m] = rn;
            ssz_g[b * M_ + m] = 0.f;
        }
    }
    if (tid < 32) {
        const float2 bb = bounds2[b * 32 + tid];
        bnds[tid] = make_float2(bb.x * ascale, bb.y * ascale);
    }
    __syncthreads();

    const int wave = tid >> 6, lane = tid & 63;
    const int nw = n0 + wave * RPW;

    float xv[RPW], yv[RPW], zv[RPW], r2[RPW], ux[RPW], uy[RPW], uz[RPW];
    #pragma unroll
    for (int r = 0; r < RPW; ++r) {
        const float4 q = xyz1s[b * N_ + nw + r];
        xv[r] = q.x * ascale; yv[r] = q.y * ascale; zv[r] = q.z * ascale;
        r2[r] = xv[r] * xv[r] + yv[r] * yv[r] + zv[r] * zv[r];
        ux[r] = xv[r] + xv[r]; uy[r] = yv[r] + yv[r]; uz[r] = zv[r] + zv[r];
    }

    unsigned mf = 0xffffffffu, mp = 0u;
    if (domask) {
        mf = 0u;
        for (int k = 0; k < 32; ++k) {
            const float2 bb = bnds[k];
            float t2 = 1e30f;
            #pragma unroll
            for (int r = 0; r < RPW; ++r) {
                const float t = fmaxf(fmaxf(bb.x - xv[r], xv[r] - bb.y), 0.f);
                t2 = fminf(t2, t * t);
            }
            if (t2 * 4.f <= 160.f)  mf |= (1u << k);
            else if (t2 <= 160.f)   mp |= (1u << k);
        }
    }
    const unsigned alive = mf | mp;

    float accd[RPW], accc[RPW], p[RPW];
    #pragma unroll
    for (int r = 0; r < RPW; ++r) { accd[r] = 0.f; accc[r] = 0.f; p[r] = 0.f; }

    if (has_p2 && has_p1 && domask) {
        if (mf == 0xffffffffu) {
            // DENSE dot-form path: t = (u.v - q2) - r2 = -s2
            #pragma unroll 4
            for (int k = 0; k < 32; ++k) {
                const int kk = (k << 6) + lane;
                const float4 c  = sp[kk];
                const float2 gq = sgq[kk];
                #pragma unroll
                for (int r = 0; r < RPW; ++r) {
                    const float arg = ux[r]*c.x + uy[r]*c.y + uz[r]*c.z + gq.y;
                    const float t  = arg - r2[r];                  // -s2
                    const float ec = __builtin_amdgcn_exp2f(t);
                    const float e  = __builtin_amdgcn_exp2f(4.f * t) * gq.x;
                    accd[r] += e;
                    accc[r] += e * __builtin_amdgcn_sqrtf(fmaxf(-t, 0.f));
                    p[r] += ec * c.w;
                }
            }
        } else {
            // masked path (early steps): exact squared-difference form
            for (int k = 0; k < 32; ++k) {
                if (!((alive >> k) & 1u)) continue;
                const int kk = (k << 6) + lane;
                const float4 c = sp[kk];
                if ((mf >> k) & 1u) {
                    const float g = sgq[kk].x;
                    #pragma unroll
                    for (int r = 0; r < RPW; ++r) {
                        const float dx = xv[r]-c.x, dy = yv[r]-c.y, dz = zv[r]-c.z;
                        const float s2 = dx*dx + dy*dy + dz*dz;
                        const float ec = __builtin_amdgcn_exp2f(-s2);
                        const float e  = __builtin_amdgcn_exp2f(-4.f * s2) * g;
                        accd[r] += e;
                        accc[r] += e * __builtin_amdgcn_sqrtf(s2);
                        p[r] += ec * c.w;
                    }
                } else {
                    #pragma unroll
                    for (int r = 0; r < RPW; ++r) {
                        const float dx = xv[r]-c.x, dy = yv[r]-c.y, dz = zv[r]-c.z;
                        const float s2 = dx*dx + dy*dy + dz*dz;
                        p[r] += __builtin_amdgcn_exp2f(-s2) * c.w;
                    }
                }
            }
        }
    } else if (!has_p2) {
        // s=0: p-only, heavily masked
        for (int k = 0; k < 32; ++k) {
            if (!((alive >> k) & 1u)) continue;
            const int kk = (k << 6) + lane;
            const float4 c = sp[kk];
            #pragma unroll
            for (int r = 0; r < RPW; ++r) {
                const float dx = xv[r]-c.x, dy = yv[r]-c.y, dz = zv[r]-c.z;
                const float s2 = dx*dx + dy*dy + dz*dz;
                p[r] += __builtin_amdgcn_exp2f(-s2) * c.w;
            }
        }
    } else if (has_p1) {
        // s=9: dense dot-form (l2c == 0 -> p-term is rn)
        #pragma unroll 4
        for (int k = 0; k < 32; ++k) {
            const int kk = (k << 6) + lane;
            const float4 c  = sp[kk];
            const float2 gq = sgq[kk];
            #pragma unroll
            for (int r = 0; r < RPW; ++r) {
                const float arg = ux[r]*c.x + uy[r]*c.y + uz[r]*c.z + gq.y;
                const float t  = arg - r2[r];                  // -s2
                const float e  = __builtin_amdgcn_exp2f(t) * gq.x;
                accd[r] += e;
                accc[r] += e * __builtin_amdgcn_sqrtf(fmaxf(-t, 0.f));
                p[r] += c.w;
            }
        }
    } else {
        // s=10: dense, no exp (e = g exactly; ascale = 1)
        #pragma unroll 4
        for (int k = 0; k < 32; ++k) {
            const int kk = (k << 6) + lane;
            const float4 c = sp[kk];
            const float  g = sgq[kk].x;
            #pragma unroll
            for (int r = 0; r < RPW; ++r) {
                const float dx = xv[r]-c.x, dy = yv[r]-c.y, dz = zv[r]-c.z;
                const float s2 = dx*dx + dy*dy + dz*dz;
                accd[r] += g;
                accc[r] += g * __builtin_amdgcn_sqrtf(s2);
            }
        }
    }

    if (has_p2) {
        #pragma unroll
        for (int r = 0; r < RPW; ++r) {
            #pragma unroll
            for (int off = 32; off >= 1; off >>= 1) {
                accd[r] += __shfl_xor(accd[r], off, 64);
                accc[r] += __shfl_xor(accc[r], off, 64);
            }
        }
    }
    if (has_p1) {
        #pragma unroll
        for (int r = 0; r < RPW; ++r) {
            #pragma unroll
            for (int off = 32; off >= 1; off >>= 1)
                p[r] += __shfl_xor(p[r], off, 64);
        }
    }

    float rl_new[RPW];
    float cw = 0.f;
    if (has_p2) {
        #pragma unroll
        for (int r = 0; r < RPW; ++r) {
            const int idx = b * N_ + nw + r;
            const float fo = fb[idx];
            const float rl = rLb[idx];
            rl_new[r] = fmaxf(rl - fo * accd[r], 0.f);
            cw += fo * accc[r];
        }
    } else {
        #pragma unroll
        for (int r = 0; r < RPW; ++r) rl_new[r] = 1.f;
    }
    if (lane == 0) wcost[wave] = cw * inva;

    if (has_p1) {
        float fn[RPW];
        #pragma unroll
        for (int r = 0; r < RPW; ++r)
            fn[r] = rl_new[r] / (p[r] + EPS);
        if (lane == 0) {
            #pragma unroll
            for (int r = 0; r < RPW; ++r) {
                const int idx = b * N_ + nw + r;
                fb[idx]  = fn[r];
                rLb[idx] = rl_new[r];
            }
        }
        if (!lcz) {
            float ssp[32];
            if (alive == 0xffffffffu) {
                // DENSE dot-form colsum: 3 fma + 1 sub + 1 trans + 1 fma
                #pragma unroll 4
                for (int k = 0; k < 32; ++k) {
                    const int kk = (k << 6) + lane;
                    const float4 c = sp[kk];
                    const float nq2 = sgq[kk].y;
                    float acc = 0.f;
                    #pragma unroll
                    for (int r = 0; r < RPW; ++r) {
                        const float arg = ux[r]*c.x + uy[r]*c.y + uz[r]*c.z + nq2;
                        const float t  = arg - r2[r];              // -s2
                        acc += __builtin_amdgcn_exp2f(t) * fn[r];
                    }
                    ssp[k] = acc * c.w;
                }
            } else {
                for (int k = 0; k < 32; ++k) {
                    float sv = 0.f;
                    if ((alive >> k) & 1u) {
                        const int kk = (k << 6) + lane;
                        const float4 c = sp[kk];
                        float acc = 0.f;
                        #pragma unroll
                        for (int r = 0; r < RPW; ++r) {
                            const float dx = xv[r]-c.x, dy = yv[r]-c.y, dz = zv[r]-c.z;
                            const float s2 = dx*dx + dy*dy + dz*dz;
                            acc += __builtin_amdgcn_exp2f(-s2) * fn[r];
                        }
                        sv = acc * c.w;
                    }
                    ssp[k] = sv;
                }
            }
            __syncthreads();
            #pragma unroll
            for (int k = 0; k < 32; ++k)
                ssl[wave * M_ + (k << 6) + lane] = ssp[k];
            __syncthreads();
            if (tid == 0 && has_p2) {
                float t = 0.f;
                #pragma unroll
                for (int w = 0; w < WAVES; ++w) t += wcost[w];
                atomicAdd(&out[b], t);
            }
            for (int m = tid; m < M_; m += THREADS) {
                const float sval = ssl[m]        + ssl[M_ + m]   + ssl[2*M_ + m]
                                 + ssl[3*M_ + m] + ssl[4*M_ + m] + ssl[5*M_ + m]
                                 + ssl[6*M_ + m] + ssl[7*M_ + m];
                if (sval != 0.f) atomicAdd(&ssc_g[b * M_ + m], sval);
            }
        } else {
            if (lane == 0) sfn_l[wave] = fn[0] + fn[1] + fn[2] + fn[3];
            __syncthreads();
            if (tid == 0 && has_p2) {
                float t = 0.f;
                #pragma unroll
                for (int w = 0; w < WAVES; ++w) t += wcost[w];
                atomicAdd(&out[b], t);
            }
            float tot = 0.f;
            #pragma unroll
            for (int w = 0; w < WAVES; ++w) tot += sfn_l[w];
            for (int m = tid; m < M_; m += THREADS) {
                const float v = sp[m].w * tot;
                if (v != 0.f) atomicAdd(&ssc_g[b * M_ + m], v);
            }
        }
    } else {
        __syncthreads();
        if (tid == 0) {
            float t = 0.f;
            #pragma unroll
            for (int w = 0; w < WAVES; ++w) t += wcost[w];
            atomicAdd(&out[b], t);
        }
    }
}

extern "C" void kernel_launch(void* const* d_in, const int* in_sizes, int n_in,
                              void* d_out, int out_size, void* d_ws, size_t ws_size,
                              hipStream_t stream) {
    const float* xyz1 = (const float*)d_in[0];
    const float* xyz2 = (const float*)d_in[1];
    float* out = (float*)d_out;
    float* ws = (float*)d_ws;
    const int SZ = B_ * N_;          // == B_*M_ == 16384
    float* rL  = ws;
    float* fb  = ws + SZ;
    float* rRb[2] = { ws + 2*SZ, ws + 3*SZ };
    float* ssb[3] = { ws + 4*SZ, ws + 5*SZ, ws + 6*SZ };
    float2* bounds2 = (float2*)(ws + 7*SZ);
    float4* xyz1s   = (float4*)(ws + 7*SZ + 512);
    float4* xyz2s   = xyz1s + (size_t)B_ * N_;

    init_kernel<<<(SZ + 255) / 256, 256, 0, stream>>>(rL, fb, ssb[0], out);
    sort_kernel<<<2 * B_, 1024, 0, stream>>>(xyz1, xyz2, xyz1s, xyz2s, bounds2);

    constexpr float LOG2E = 1.4426950408889634f;
    static const float levels[10] = {
        -16384.f, -4096.f, -1024.f, -256.f, -64.f,
        -16.f, -4.f, -1.f, -0.25f, 0.f
    };
    for (int s = 0; s <= 10; ++s) {
        const int has_p2 = (s > 0);
        const int has_p1 = (s < 10);
        const int domask = (s <= 8);
        const int lcz    = (s == 9);
        const float lvl  = (s <= 8) ? levels[s] : levels[8];
        const float ascale = (s == 10) ? 1.f : sqrtf(-(lvl * LOG2E));
        const float inva   = 1.f / ascale;
        fused_step<<<GRID, THREADS, 0, stream>>>(
            xyz1s, xyz2s, bounds2, rL, fb,
            rRb[(s + 1) & 1], rRb[s & 1],
            ssb[(s + 2) % 3], ssb[s % 3], ssb[(s + 1) % 3],
            out, ascale, inva, has_p2, has_p1, domask, lcz);
    }
}